// Round 10
// baseline (75.434 us; speedup 1.0000x reference)
//
#include <hip/hip_runtime.h>
#include <math.h>
#include <limits.h>

#define NN 8192
#define DD 128
#define BM 256        // rows per block (4 waves x 64)
#define BN 64         // cols per j-tile
#define NPART 16      // grid = 32*16 = 512 blocks (single batch)
#define JRANGE (NN / NPART)    // 512
#define NTILES (JRANGE / BN)   // 8

typedef __attribute__((ext_vector_type(4))) int i32x4;

// ws byte offsets
#define WS_PARTIAL 0                        // 4 KB (1024 floats)
#define WS_SCALE   4096                     // 64 B
#define WS_CB      (4096 + 256)             // chunkBase 2048 int = 8 KB
#define WS_IPERM   (WS_CB + 8192)           // 32 KB
#define WS_LABS    (WS_IPERM + 32768)       // 32 KB
#define WS_CLS     (WS_LABS + 32768)        // 2 KB (512 int)
#define WS_MD      (WS_CLS + 2048)          // 64 KB (8192 int2)
#define WS_HPK     (WS_MD + 65536)          // 32 KB
#define WS_HNK     (WS_HPK + 32768)         // 32 KB
#define WS_AH      (WS_HNK + 32768)         // 1 MB
#define WS_AL      (WS_AH + NN * DD)        // 1 MB

// pass 1: per-block absmax partials
__global__ __launch_bounds__(256)
void prep_k(const float* __restrict__ emb, float* __restrict__ partial) {
    int i = blockIdx.x * 256 + threadIdx.x;          // float4 index
    float4 v = reinterpret_cast<const float4*>(emb)[i];
    float m = fmaxf(fmaxf(fabsf(v.x), fabsf(v.y)), fmaxf(fabsf(v.z), fabsf(v.w)));
#pragma unroll
    for (int off = 1; off < 64; off <<= 1) m = fmaxf(m, __shfl_xor(m, off, 64));
    __shared__ float sm[4];
    if ((threadIdx.x & 63) == 0) sm[threadIdx.x >> 6] = m;
    __syncthreads();
    if (threadIdx.x == 0)
        partial[blockIdx.x] = fmaxf(fmaxf(sm[0], sm[1]), fmaxf(sm[2], sm[3]));
}

// label histogram (32 chunks x 64 classes) + class prefix + per-chunk base
__global__ __launch_bounds__(1024)
void hist_k(const int* __restrict__ lab, int* __restrict__ chunkBase) {
    __shared__ int H[32][64];
    __shared__ int base[64];
    for (int i = threadIdx.x; i < 2048; i += 1024) (&H[0][0])[i] = 0;
    __syncthreads();
    for (int r = threadIdx.x; r < NN; r += 1024)
        atomicAdd(&H[r >> 8][lab[r] & 63], 1);
    __syncthreads();
    if (threadIdx.x == 0) {
        int run = 0;
        for (int c = 0; c < 64; ++c) {
            int tot = 0;
            for (int b = 0; b < 32; ++b) tot += H[b][c];
            base[c] = run; run += tot;
        }
    }
    __syncthreads();
    for (int i = threadIdx.x; i < 2048; i += 1024) {
        int b = i >> 6, c = i & 63;
        int off = base[c];
        for (int b2 = 0; b2 < b; ++b2) off += H[b2][c];
        chunkBase[i] = off;   // layout [chunk][class]
    }
}

// stable rank within chunk -> scatter permutation (deterministic)
__global__ __launch_bounds__(256)
void rank_k(const int* __restrict__ lab, const int* __restrict__ chunkBase,
            int* __restrict__ iperm, int* __restrict__ labS) {
    __shared__ int L[256];
    int r = blockIdx.x * 256 + threadIdx.x;
    int my = lab[r] & 63;
    L[threadIdx.x] = my;
    __syncthreads();
    int cnt = 0;
    for (int t = 0; t < threadIdx.x; ++t) cnt += (L[t] == my) ? 1 : 0;
    int rank = chunkBase[blockIdx.x * 64 + my] + cnt;
    iperm[rank] = r;
    labS[rank]  = my;
}

// global amax reduce + permuted i8 hi/lo quantize + int metadata + cls16 + key init
__global__ __launch_bounds__(256)
void quantize_k(const float* __restrict__ emb, const float* __restrict__ partial,
                const int* __restrict__ iperm, const int* __restrict__ labS,
                int* __restrict__ aH, int* __restrict__ aL, int2* __restrict__ md,
                int* __restrict__ cls, int* __restrict__ hpK, int* __restrict__ hnK,
                float* __restrict__ scale) {
    __shared__ float sm[4];
    float m = fmaxf(fmaxf(partial[threadIdx.x], partial[threadIdx.x + 256]),
                    fmaxf(partial[threadIdx.x + 512], partial[threadIdx.x + 768]));
#pragma unroll
    for (int off = 1; off < 64; off <<= 1) m = fmaxf(m, __shfl_xor(m, off, 64));
    if ((threadIdx.x & 63) == 0) sm[threadIdx.x >> 6] = m;
    __syncthreads();
    float amax = fmaxf(fmaxf(fmaxf(sm[0], sm[1]), fmaxf(sm[2], sm[3])), 1e-30f);
    float sA  = amax * (1.0f / 127.0f);
    float inv = 127.0f / amax;
    float mm  = sA * sA * (1.0f / 128.0f);   // d2_true = mm * d2_int

    const int lane = threadIdx.x & 63;
    const int w    = threadIdx.x >> 6;
    const int half = lane >> 5;
    const int l32  = lane & 31;
    const int row  = blockIdx.x * 8 + w * 2 + half;   // sorted row
    const int orow = iperm[row];

    float4 v = reinterpret_cast<const float4*>(emb)[orow * 32 + l32];
    float s = 0.f;
    s = fmaf(v.x, v.x, s); s = fmaf(v.y, v.y, s);
    s = fmaf(v.z, v.z, s); s = fmaf(v.w, v.w, s);
#pragma unroll
    for (int off = 1; off < 32; off <<= 1) s += __shfl_xor(s, off, 64);

    int h = 0, l = 0;
#define QSTEP(X, K) { \
        float a = rintf((X) * inv); \
        a = fminf(fmaxf(a, -127.f), 127.f); \
        float r_ = fmaf(-a, sA, (X)); \
        float b = rintf(r_ * inv * 256.0f); \
        b = fminf(fmaxf(b, -127.f), 127.f); \
        h |= ((int)a & 255) << (8 * (K)); \
        l |= ((int)b & 255) << (8 * (K)); }
    QSTEP(v.x, 0) QSTEP(v.y, 1) QSTEP(v.z, 2) QSTEP(v.w, 3)
#undef QSTEP
    aH[row * 32 + l32] = h;
    aL[row * 32 + l32] = l;
    if (l32 == 0) md[row] = make_int2((int)rintf(s / mm), labS[row]);
    if (blockIdx.x < 32 && threadIdx.x < 16) {
        int g = blockIdx.x * 16 + threadIdx.x;
        cls[g] = labS[g * 16] | (labS[g * 16 + 15] << 8);
    }
    if (threadIdx.x < 8) {
        int r0 = blockIdx.x * 8 + threadIdx.x;
        hpK[r0] = INT_MIN;
        hnK[r0] = INT_MAX;
    }
    if (blockIdx.x == 0 && threadIdx.x == 0) scale[0] = mm;
}

__global__ __launch_bounds__(256, 2)
void hardest_k(const int* __restrict__ aH, const int* __restrict__ aL,
               const int2* __restrict__ md, const int* __restrict__ cls,
               int* __restrict__ hpK, int* __restrict__ hnK) {
    const int tid  = threadIdx.x;
    const int w    = tid >> 6;
    const int lane = tid & 63;
    const int lrow = lane & 15;
    const int lk   = lane >> 4;
    const int ib   = (int)blockIdx.x >> 4;    // 0..31
    const int part = (int)blockIdx.x & 15;    // 0..15
    const int i0   = ib * BM;
    const int jbeg = part * JRANGE;

    // block class range (rows sorted by label => [first row's lab, last row's lab])
    const int bLo = cls[i0 >> 4] & 255;
    const int bHi = cls[(i0 + BM - 16) >> 4] >> 8;

    // persistent A fragments: 4 strips of 16 rows, K=128 in 2 chunks, hi+lo
    i32x4 ah[4][2], al[4][2];
#pragma unroll
    for (int s = 0; s < 4; ++s) {
        int row = i0 + w * 64 + s * 16 + lrow;
#pragma unroll
        for (int q = 0; q < 2; ++q) {
            ah[s][q] = *reinterpret_cast<const i32x4*>(&aH[row * 32 + q * 16 + lk * 4]);
            al[s][q] = *reinterpret_cast<const i32x4*>(&aL[row * 32 + q * 16 + lk * 4]);
        }
    }
    int li[4][4], hp[4][4], hn[4][4];
#pragma unroll
    for (int s = 0; s < 4; ++s)
#pragma unroll
        for (int t = 0; t < 4; ++t) {
            li[s][t] = md[i0 + w * 64 + s * 16 + lk * 4 + t].y;
            hp[s][t] = INT_MIN;
            hn[s][t] = INT_MAX;
        }

#pragma unroll 1
    for (int jt = 0; jt < NTILES; ++jt) {
        const int j0 = jbeg + jt * BN;
#pragma unroll
        for (int c = 0; c < 4; ++c) {
            const int jrow = j0 + c * 16 + lrow;
            i32x4 bh0 = *reinterpret_cast<const i32x4*>(&aH[jrow * 32 + 0  + lk * 4]);
            i32x4 bh1 = *reinterpret_cast<const i32x4*>(&aH[jrow * 32 + 16 + lk * 4]);
            i32x4 bl0 = *reinterpret_cast<const i32x4*>(&aL[jrow * 32 + 0  + lk * 4]);
            i32x4 bl1 = *reinterpret_cast<const i32x4*>(&aL[jrow * 32 + 16 + lk * 4]);
            int2 mj = md[jrow];
            i32x4 accA[4], accB[4];
            i32x4 zero = {0, 0, 0, 0};
#pragma unroll
            for (int s = 0; s < 4; ++s) { accA[s] = zero; accB[s] = zero; }
#pragma unroll
            for (int s = 0; s < 4; ++s) {
                accA[s] = __builtin_amdgcn_mfma_i32_16x16x64_i8(ah[s][0], bh0, accA[s], 0, 0, 0);
                accA[s] = __builtin_amdgcn_mfma_i32_16x16x64_i8(ah[s][1], bh1, accA[s], 0, 0, 0);
                accB[s] = __builtin_amdgcn_mfma_i32_16x16x64_i8(ah[s][0], bl0, accB[s], 0, 0, 0);
                accB[s] = __builtin_amdgcn_mfma_i32_16x16x64_i8(ah[s][1], bl1, accB[s], 0, 0, 0);
                accB[s] = __builtin_amdgcn_mfma_i32_16x16x64_i8(al[s][0], bh0, accB[s], 0, 0, 0);
                accB[s] = __builtin_amdgcn_mfma_i32_16x16x64_i8(al[s][1], bh1, accB[s], 0, 0, 0);
            }
            const int qs = mj.x, lj = mj.y;
            const int jc  = cls[(j0 + c * 16) >> 4];   // uniform scalar
            const int jLo = jc & 255, jHi = jc >> 8;
            if (bHi < jLo || bLo > jHi) {
                // no same-class pair possible in this tile: 3-op epilogue
#pragma unroll
                for (int s = 0; s < 4; ++s)
#pragma unroll
                    for (int t = 0; t < 4; ++t) {
                        int e = accA[s][t] * 256 + accB[s][t];   // exact, |e| < 2^30
                        hn[s][t] = min(hn[s][t], qs - e);
                    }
            } else {
#pragma unroll
                for (int s = 0; s < 4; ++s)
#pragma unroll
                    for (int t = 0; t < 4; ++t) {
                        int e = accA[s][t] * 256 + accB[s][t];
                        int g = qs - e;                          // (sqj - 2*dot)/mm
                        bool same = (li[s][t] == lj);
                        hp[s][t] = max(hp[s][t], same ? g : INT_MIN);
                        hn[s][t] = min(hn[s][t], same ? INT_MAX : g);
                    }
            }
        }
    }
    // reduce over the 16 column-lanes sharing each output row (int domain)
#pragma unroll
    for (int off = 1; off < 16; off <<= 1)
#pragma unroll
        for (int s = 0; s < 4; ++s)
#pragma unroll
            for (int t = 0; t < 4; ++t) {
                hp[s][t] = max(hp[s][t], __shfl_xor(hp[s][t], off, 64));
                hn[s][t] = min(hn[s][t], __shfl_xor(hn[s][t], off, 64));
            }
    if (lrow == 0) {
#pragma unroll
        for (int s = 0; s < 4; ++s)
#pragma unroll
            for (int t = 0; t < 4; ++t) {
                int i = i0 + w * 64 + s * 16 + lk * 4 + t;
                atomicMax(&hpK[i], hp[s][t]);   // order-independent => deterministic
                atomicMin(&hnK[i], hn[s][t]);
            }
    }
}

__global__ __launch_bounds__(1024)
void final_k(const int* __restrict__ hpK, const int* __restrict__ hnK,
             const int2* __restrict__ md, const float* __restrict__ scale,
             float* __restrict__ out) {
    const float mm = scale[0];
    float total = 0.f, cnt = 0.f;
    for (int i = threadIdx.x; i < NN; i += 1024) {
        float sqi = mm * (float)md[i].x;
        float hp2 = fmaf(mm, (float)hpK[i], sqi);   // d^2 = sq_i + mm*g
        float hn2 = fmaf(mm, (float)hnK[i], sqi);   // INT_MAX sentinel -> huge -> excluded
        float hpd = sqrtf(fmaxf(hp2, 0.f));
        float hnd = sqrtf(fmaxf(hn2, 0.f));
        float tl = hpd - hnd + 1.0f;
        if (tl > 0.f) { total += tl; cnt += 1.f; }
    }
#pragma unroll
    for (int off = 1; off < 64; off <<= 1) {
        total += __shfl_xor(total, off, 64);
        cnt   += __shfl_xor(cnt,   off, 64);
    }
    __shared__ float sT[16], sC[16];
    int wave = threadIdx.x >> 6;
    if ((threadIdx.x & 63) == 0) { sT[wave] = total; sC[wave] = cnt; }
    __syncthreads();
    if (threadIdx.x == 0) {
        float T = 0.f, Cn = 0.f;
#pragma unroll
        for (int k = 0; k < 16; ++k) { T += sT[k]; Cn += sC[k]; }
        out[0] = (Cn > 0.f) ? T / Cn : 0.f;
    }
}

extern "C" void kernel_launch(void* const* d_in, const int* in_sizes, int n_in,
                              void* d_out, int out_size, void* d_ws, size_t ws_size,
                              hipStream_t stream) {
    const float* emb = (const float*)d_in[0];
    const int*   lab = (const int*)d_in[1];
    char* ws = (char*)d_ws;
    float* partial   = (float*)(ws + WS_PARTIAL);
    float* scale     = (float*)(ws + WS_SCALE);
    int*   chunkBase = (int*)(ws + WS_CB);
    int*   iperm     = (int*)(ws + WS_IPERM);
    int*   labS      = (int*)(ws + WS_LABS);
    int*   cls       = (int*)(ws + WS_CLS);
    int2*  md        = (int2*)(ws + WS_MD);
    int*   hpK       = (int*)(ws + WS_HPK);
    int*   hnK       = (int*)(ws + WS_HNK);
    int*   aH        = (int*)(ws + WS_AH);
    int*   aL        = (int*)(ws + WS_AL);

    prep_k<<<dim3(1024), dim3(256), 0, stream>>>(emb, partial);
    hist_k<<<dim3(1), dim3(1024), 0, stream>>>(lab, chunkBase);
    rank_k<<<dim3(32), dim3(256), 0, stream>>>(lab, chunkBase, iperm, labS);
    quantize_k<<<dim3(NN / 8), dim3(256), 0, stream>>>(emb, partial, iperm, labS,
                                                       aH, aL, md, cls, hpK, hnK, scale);
    hardest_k<<<dim3((NN / BM) * NPART), dim3(256), 0, stream>>>(aH, aL, md, cls, hpK, hnK);
    final_k<<<dim3(1), dim3(1024), 0, stream>>>(hpK, hnK, md, scale, (float*)d_out);
}

// Round 11
// 48.299 us; speedup vs baseline: 1.5618x; 1.5618x over previous
//
#include <hip/hip_runtime.h>
#include <math.h>

#define NN 8192
#define DD 128
#define BM 256        // rows per block (4 waves x 64)
#define BN 64         // cols per j-tile
#define NPART 16      // grid = 32*16 = 512 blocks (2 blocks/CU, single batch)
#define JRANGE (NN / NPART)    // 512
#define NTILES (JRANGE / BN)   // 8

typedef __attribute__((ext_vector_type(4))) int i32x4;

// ws byte offsets
#define WS_SJC 0                          // 8192 * float4 = 128 KB
#define WS_HPK (NN * 16)                  // 32 KB (uint keys)
#define WS_HNK (WS_HPK + NN * 4)          // 32 KB
#define WS_AH  (WS_HNK + NN * 4)          // 1 MB (fragment-contiguous layout)
#define WS_AL  (WS_AH + NN * DD)          // 1 MB

// order-preserving float -> uint key (unsigned compare == float compare)
__device__ __forceinline__ unsigned fkey(float f) {
    unsigned u = __float_as_uint(f);
    return (u & 0x80000000u) ? ~u : (u | 0x80000000u);
}
__device__ __forceinline__ float fkey_inv(unsigned k) {
    unsigned u = (k & 0x80000000u) ? (k ^ 0x80000000u) : ~k;
    return __uint_as_float(u);
}

// fused: per-row sqnorm + absmax + i8 hi/lo quantize + metadata pack + key init
// quantized ints stored FRAGMENT-CONTIGUOUS:
//   int_index(row, k_int) = (row>>4)*512 + (k_int>>4)*256 + ((k_int>>2)&3)*64
//                         + (row&15)*4 + (k_int&3)
// so a wave's MFMA fragment load is  base(g,q) + lane*16 bytes  (1KB contiguous).
__global__ __launch_bounds__(256)
void prepq_k(const float* __restrict__ emb, const int* __restrict__ lab,
             float4* __restrict__ sjc, unsigned* __restrict__ hpK,
             unsigned* __restrict__ hnK, int* __restrict__ aH, int* __restrict__ aL) {
    const int lane = threadIdx.x & 63;
    const int w    = threadIdx.x >> 6;
    const int half = lane >> 5;
    const int l32  = lane & 31;
    const int row  = blockIdx.x * 8 + w * 2 + half;

    float4 v = reinterpret_cast<const float4*>(emb)[row * 32 + l32];
    float s = 0.f, m = 0.f;
    s = fmaf(v.x, v.x, s); m = fmaxf(m, fabsf(v.x));
    s = fmaf(v.y, v.y, s); m = fmaxf(m, fabsf(v.y));
    s = fmaf(v.z, v.z, s); m = fmaxf(m, fabsf(v.z));
    s = fmaf(v.w, v.w, s); m = fmaxf(m, fabsf(v.w));
#pragma unroll
    for (int off = 1; off < 32; off <<= 1) {   // stays within the 32-lane half
        s += __shfl_xor(s, off, 64);
        m = fmaxf(m, __shfl_xor(m, off, 64));
    }
    m = fmaxf(m, 1e-30f);
    float sA  = m * (1.0f / 127.0f);
    float inv = 127.0f / m;
    int h = 0, l = 0;
#define QSTEP(X, K) { \
        float a = rintf((X) * inv); \
        a = fminf(fmaxf(a, -127.f), 127.f); \
        float r = fmaf(-a, sA, (X)); \
        float b = rintf(r * inv * 256.0f); \
        b = fminf(fmaxf(b, -127.f), 127.f); \
        h |= ((int)a & 255) << (8 * (K)); \
        l |= ((int)b & 255) << (8 * (K)); }
    QSTEP(v.x, 0) QSTEP(v.y, 1) QSTEP(v.z, 2) QSTEP(v.w, 3)
#undef QSTEP
    // fragment-contiguous scatter (k_int = l32)
    const int nidx = (row >> 4) * 512 + (l32 >> 4) * 256 + ((l32 >> 2) & 3) * 64
                   + (row & 15) * 4 + (l32 & 3);
    aH[nidx] = h;
    aL[nidx] = l;
    if (l32 == 0) {
        // ci = sA * sqrt(2)/16 so ci_i*ci_j = 2*sAi*sAj/256
        sjc[row] = make_float4(s, sA * 0.08838834764831845f,
                               __int_as_float(lab[row]), 0.f);
    }
    if (threadIdx.x < 8) {
        int r0 = blockIdx.x * 8 + threadIdx.x;
        hpK[r0] = 0x007FFFFFu;   // fkey(-inf)
        hnK[r0] = 0xFF800000u;   // fkey(+inf)
    }
}

__global__ __launch_bounds__(256, 2)
void hardest_k(const int* __restrict__ aH, const int* __restrict__ aL,
               const float4* __restrict__ sjc,
               unsigned* __restrict__ hpK, unsigned* __restrict__ hnK) {
    const int tid  = threadIdx.x;
    const int w    = tid >> 6;
    const int lane = tid & 63;
    const int lrow = lane & 15;
    const int lk   = lane >> 4;
    const int ib   = (int)blockIdx.x >> 4;    // 0..31
    const int part = (int)blockIdx.x & 15;    // 0..15
    const int i0   = ib * BM;
    const int jbeg = part * JRANGE;

    // persistent A fragments: 4 strips of 16 rows, K=128 in 2 chunks, hi+lo
    // fragment-contiguous: load = base(g,q) + lane*4 ints (1KB contiguous/wave)
    i32x4 ah[4][2], al[4][2];
#pragma unroll
    for (int s = 0; s < 4; ++s) {
        const int gA = ib * 16 + w * 4 + s;
#pragma unroll
        for (int q = 0; q < 2; ++q) {
            ah[s][q] = *reinterpret_cast<const i32x4*>(&aH[gA * 512 + q * 256 + lane * 4]);
            al[s][q] = *reinterpret_cast<const i32x4*>(&aL[gA * 512 + q * 256 + lane * 4]);
        }
    }
    int   li[4][4];
    float cih[4][4], hpg[4][4], hng[4][4];
#pragma unroll
    for (int s = 0; s < 4; ++s)
#pragma unroll
        for (int t = 0; t < 4; ++t) {
            float4 md = sjc[i0 + w * 64 + s * 16 + lk * 4 + t];
            li[s][t]  = __float_as_int(md.z);
            cih[s][t] = md.y;
            hpg[s][t] = -INFINITY;
            hng[s][t] =  INFINITY;
        }

#pragma unroll 1
    for (int jt = 0; jt < NTILES; ++jt) {
        const int j0 = jbeg + jt * BN;
#pragma unroll
        for (int c = 0; c < 4; ++c) {
            const int gB = (j0 >> 4) + c;
            const int bb = gB * 512 + lane * 4;
            i32x4 bh0 = *reinterpret_cast<const i32x4*>(&aH[bb]);
            i32x4 bh1 = *reinterpret_cast<const i32x4*>(&aH[bb + 256]);
            i32x4 bl0 = *reinterpret_cast<const i32x4*>(&aL[bb]);
            i32x4 bl1 = *reinterpret_cast<const i32x4*>(&aL[bb + 256]);
            float4 sv = sjc[j0 + c * 16 + lrow];
            i32x4 accA[4], accB[4];
            i32x4 zero = {0, 0, 0, 0};
#pragma unroll
            for (int s = 0; s < 4; ++s) { accA[s] = zero; accB[s] = zero; }
#pragma unroll
            for (int s = 0; s < 4; ++s) {
                accA[s] = __builtin_amdgcn_mfma_i32_16x16x64_i8(ah[s][0], bh0, accA[s], 0, 0, 0);
                accA[s] = __builtin_amdgcn_mfma_i32_16x16x64_i8(ah[s][1], bh1, accA[s], 0, 0, 0);
                accB[s] = __builtin_amdgcn_mfma_i32_16x16x64_i8(ah[s][0], bl0, accB[s], 0, 0, 0);
                accB[s] = __builtin_amdgcn_mfma_i32_16x16x64_i8(ah[s][1], bl1, accB[s], 0, 0, 0);
                accB[s] = __builtin_amdgcn_mfma_i32_16x16x64_i8(al[s][0], bh0, accB[s], 0, 0, 0);
                accB[s] = __builtin_amdgcn_mfma_i32_16x16x64_i8(al[s][1], bh1, accB[s], 0, 0, 0);
            }
            const float sqj = sv.x;
            const float cjv = sv.y;
            const int   lj  = __float_as_int(sv.z);
#pragma unroll
            for (int s = 0; s < 4; ++s)
#pragma unroll
                for (int t = 0; t < 4; ++t) {
                    int   e  = (accA[s][t] << 8) + accB[s][t];    // exact, < 2^30
                    float ef = (float)e;
                    float mm = cih[s][t] * cjv;                   // 2*sAi*sAj/256
                    float gg = fmaf(mm, -ef, sqj);                // g = sqj - 2*dot
                    bool same = (li[s][t] == lj);
                    hpg[s][t] = fmaxf(hpg[s][t], same ? gg : -INFINITY);
                    hng[s][t] = fminf(hng[s][t], same ? INFINITY : gg);
                }
        }
    }

    // reduce over the 16 column-lanes sharing each output row
#pragma unroll
    for (int off = 1; off < 16; off <<= 1)
#pragma unroll
        for (int s = 0; s < 4; ++s)
#pragma unroll
            for (int t = 0; t < 4; ++t) {
                hpg[s][t] = fmaxf(hpg[s][t], __shfl_xor(hpg[s][t], off, 64));
                hng[s][t] = fminf(hng[s][t], __shfl_xor(hng[s][t], off, 64));
            }
    if (lrow == 0) {
#pragma unroll
        for (int s = 0; s < 4; ++s)
#pragma unroll
            for (int t = 0; t < 4; ++t) {
                int i = i0 + w * 64 + s * 16 + lk * 4 + t;
                atomicMax(&hpK[i], fkey(hpg[s][t]));   // order-independent => deterministic
                atomicMin(&hnK[i], fkey(hng[s][t]));
            }
    }
}

__global__ __launch_bounds__(1024)
void final_k(const unsigned* __restrict__ hpK, const unsigned* __restrict__ hnK,
             const float4* __restrict__ sjc, float* __restrict__ out) {
    float total = 0.f, cnt = 0.f;
    for (int i = threadIdx.x; i < NN; i += 1024) {
        float hp = fkey_inv(hpK[i]);
        float hn = fkey_inv(hnK[i]);
        float s  = sjc[i].x;
        float hp2 = s + hp, hn2 = s + hn;                 // d^2 = sq_i + g
        float hpd = (hp2 == -INFINITY) ? -INFINITY : sqrtf(fmaxf(hp2, 0.f));
        float hnd = (hn2 ==  INFINITY) ?  INFINITY : sqrtf(fmaxf(hn2, 0.f));
        float tl = hpd - hnd + 1.0f;                      // -inf propagates, no NaN
        if (tl > 0.f) { total += tl; cnt += 1.f; }
    }
#pragma unroll
    for (int off = 1; off < 64; off <<= 1) {
        total += __shfl_xor(total, off, 64);
        cnt   += __shfl_xor(cnt,   off, 64);
    }
    __shared__ float sT[16], sC[16];
    int wave = threadIdx.x >> 6;
    if ((threadIdx.x & 63) == 0) { sT[wave] = total; sC[wave] = cnt; }
    __syncthreads();
    if (threadIdx.x == 0) {
        float T = 0.f, Cn = 0.f;
#pragma unroll
        for (int k = 0; k < 16; ++k) { T += sT[k]; Cn += sC[k]; }
        out[0] = (Cn > 0.f) ? T / Cn : 0.f;
    }
}

extern "C" void kernel_launch(void* const* d_in, const int* in_sizes, int n_in,
                              void* d_out, int out_size, void* d_ws, size_t ws_size,
                              hipStream_t stream) {
    const float* emb = (const float*)d_in[0];
    const int*   lab = (const int*)d_in[1];
    char* ws = (char*)d_ws;
    float4*   sjc = (float4*)(ws + WS_SJC);
    unsigned* hpK = (unsigned*)(ws + WS_HPK);
    unsigned* hnK = (unsigned*)(ws + WS_HNK);
    int*      aH  = (int*)(ws + WS_AH);
    int*      aL  = (int*)(ws + WS_AL);

    prepq_k<<<dim3(NN / 8), dim3(256), 0, stream>>>(emb, lab, sjc, hpK, hnK, aH, aL);
    hardest_k<<<dim3((NN / BM) * NPART), dim3(256), 0, stream>>>(aH, aL, sjc, hpK, hnK);
    final_k<<<dim3(1), dim3(1024), 0, stream>>>(hpK, hnK, sjc, (float*)d_out);
}